// Round 1
// baseline (79.031 us; speedup 1.0000x reference)
//
#include <hip/hip_runtime.h>
#include <math.h>

#define B_ 4
#define T_ 512
#define C_ 128
#define HS_ 64

typedef float f4 __attribute__((ext_vector_type(4)));

// scale = C^-0.5
#define SCALE_ 0.08838834764831845f

// ---------------------------------------------------------------------------
// Kernel 1: prep.  x1 = x + pos_emb;  Aq = x1@W1q + b1;  Ak = x1@W1k; V = x@Wv
// Block: 16 rows, 320 threads. Thread = (rowgroup of 4 rows) x (col-quad of 4).
// q in [0,32): Aq cols q*4; [32,64): Ak cols; [64,80): V cols.
// ---------------------------------------------------------------------------
__global__ __launch_bounds__(320) void k_prep(
    const float* __restrict__ x, const float* __restrict__ pos,
    const float* __restrict__ W1, const float* __restrict__ b1,
    const float* __restrict__ Wv,
    float* __restrict__ Aq, float* __restrict__ Ak, float* __restrict__ V)
{
    __shared__ float x1s[16 * 128];
    __shared__ float xs[16 * 128];
    const int t = threadIdx.x;
    const int row0 = blockIdx.x * 16;  // global row base over B*T = 2048

    for (int idx = t; idx < 16 * 128; idx += 320) {
        int r = idx >> 7, c = idx & 127;
        int gr = row0 + r;
        float xv = x[gr * 128 + c];
        xs[idx] = xv;
        x1s[idx] = xv + pos[(gr & 511) * 128 + c];
    }
    __syncthreads();

    const int rg = t / 80;  // 0..3 -> rows rg*4 .. rg*4+3 within tile
    const int q = t % 80;

    const float* wbase;
    int wstr, col0;
    const float* xb;
    float* obase;
    int ostr;
    f4 binit = {0.f, 0.f, 0.f, 0.f};
    if (q < 32) {
        col0 = q * 4;
        wbase = W1 + 128 * 128 + col0;  // W1q rows
        wstr = 128;
        xb = x1s;
        obase = Aq;
        ostr = 128;
        binit = *(const f4*)(b1 + col0);
    } else if (q < 64) {
        col0 = (q - 32) * 4;
        wbase = W1 + col0;  // W1k rows
        wstr = 128;
        xb = x1s;
        obase = Ak;
        ostr = 128;
    } else {
        col0 = (q - 64) * 4;
        wbase = Wv + col0;
        wstr = 64;
        xb = xs;
        obase = V;
        ostr = 64;
    }

    f4 acc0 = binit, acc1 = binit, acc2 = binit, acc3 = binit;
    const int rbase = rg * 4 * 128;
#pragma unroll 4
    for (int c = 0; c < 128; ++c) {
        f4 w = *(const f4*)(wbase + c * wstr);
        float x0 = xb[rbase + c];
        float x1 = xb[rbase + 128 + c];
        float x2 = xb[rbase + 256 + c];
        float x3 = xb[rbase + 384 + c];
        acc0 += x0 * w;
        acc1 += x1 * w;
        acc2 += x2 * w;
        acc3 += x3 * w;
    }

    int gr = row0 + rg * 4;
    *(f4*)(obase + (gr + 0) * ostr + col0) = acc0;
    *(f4*)(obase + (gr + 1) * ostr + col0) = acc1;
    *(f4*)(obase + (gr + 2) * ostr + col0) = acc2;
    *(f4*)(obase + (gr + 3) * ostr + col0) = acc3;
}

// ---------------------------------------------------------------------------
// Kernel 2: wei.  S[b,i,j] = (sum_c relu(Aq[b,i,c]+Ak[b,j,c]) * W2[c] + b2)*scale
// One block per (b, i-tile, j-tile) with j-tile <= i-tile (causal). 32x32 tile.
// 256 threads: cs = t&3 is a 32-wide c-slice; pt = t>>2 picks a 4x4 (i,j) reg
// tile. Cross-cs reduce via shfl_xor(1),(2).
// ---------------------------------------------------------------------------
__global__ __launch_bounds__(256) void k_wei(
    const float* __restrict__ Aq, const float* __restrict__ Ak,
    const float* __restrict__ W2, const float* __restrict__ b2,
    float* __restrict__ S)
{
    __shared__ float aqs[32 * 132];  // padded stride 132 to break bank conflicts
    __shared__ float aks[32 * 132];
    __shared__ float w2s[128];

    const int bx = blockIdx.x;  // 0..135 lower-triangle tile index
    const int b = blockIdx.y;
    int it = (int)((sqrtf(8.0f * (float)bx + 1.0f) - 1.0f) * 0.5f);
    while ((it + 1) * (it + 2) / 2 <= bx) ++it;
    while (it * (it + 1) / 2 > bx) --it;
    const int jt = bx - it * (it + 1) / 2;
    const int i0 = it * 32, j0 = jt * 32;
    const int t = threadIdx.x;

    for (int idx = t; idx < 32 * 32; idx += 256) {
        int r = idx >> 5, cq = idx & 31;
        f4 a = *(const f4*)(Aq + ((b * T_ + i0 + r) * C_ + cq * 4));
        f4 k = *(const f4*)(Ak + ((b * T_ + j0 + r) * C_ + cq * 4));
        *(f4*)&aqs[r * 132 + cq * 4] = a;
        *(f4*)&aks[r * 132 + cq * 4] = k;
    }
    if (t < 32) *(f4*)&w2s[t * 4] = *(const f4*)(W2 + t * 4);
    __syncthreads();

    const int cs = t & 3;        // c-slice: c in [cs*32, cs*32+32)
    const int pt = t >> 2;       // 0..63
    const int i4 = (pt >> 3) * 4;  // row offset in tile
    const int j4 = (pt & 7) * 4;   // col offset in tile

    f4 w2r[8];
#pragma unroll
    for (int u = 0; u < 8; ++u) w2r[u] = *(const f4*)&w2s[cs * 32 + u * 4];

    f4 acc[4][4];
#pragma unroll
    for (int a = 0; a < 4; ++a)
#pragma unroll
        for (int k = 0; k < 4; ++k) acc[a][k] = (f4){0.f, 0.f, 0.f, 0.f};

#pragma unroll
    for (int u = 0; u < 8; ++u) {
        const int c = cs * 32 + u * 4;
        f4 Ar[4], Kr[4];
#pragma unroll
        for (int r = 0; r < 4; ++r) {
            Ar[r] = *(const f4*)&aqs[(i4 + r) * 132 + c];
            Kr[r] = *(const f4*)&aks[(j4 + r) * 132 + c];
        }
        f4 w = w2r[u];
#pragma unroll
        for (int a = 0; a < 4; ++a)
#pragma unroll
            for (int k = 0; k < 4; ++k) {
                f4 tt = Ar[a] + Kr[k];
                acc[a][k].x += fmaxf(tt.x, 0.f) * w.x;
                acc[a][k].y += fmaxf(tt.y, 0.f) * w.y;
                acc[a][k].z += fmaxf(tt.z, 0.f) * w.z;
                acc[a][k].w += fmaxf(tt.w, 0.f) * w.w;
            }
    }

    float sv[4][4];
#pragma unroll
    for (int a = 0; a < 4; ++a)
#pragma unroll
        for (int k = 0; k < 4; ++k) {
            f4 v = acc[a][k];
            float s = (v.x + v.y) + (v.z + v.w);
            s += __shfl_xor(s, 1);
            s += __shfl_xor(s, 2);
            sv[a][k] = s;
        }

    if (cs == 0) {
        const float b2v = b2[0];
#pragma unroll
        for (int a = 0; a < 4; ++a) {
            f4 o;
            o.x = (sv[a][0] + b2v) * SCALE_;
            o.y = (sv[a][1] + b2v) * SCALE_;
            o.z = (sv[a][2] + b2v) * SCALE_;
            o.w = (sv[a][3] + b2v) * SCALE_;
            *(f4*)(S + (size_t)(b * T_ + i0 + i4 + a) * T_ + j0 + j4) = o;
        }
    }
}

// ---------------------------------------------------------------------------
// Kernel 3: softmax over j (causal, row length i+1) + out = p @ v
// One wave per row; 4 waves per block; lane = h in [0,64).
// ---------------------------------------------------------------------------
__global__ __launch_bounds__(256) void k_out(
    const float* __restrict__ S, const float* __restrict__ V,
    float* __restrict__ out)
{
    __shared__ float pbuf[4][512];
    const int t = threadIdx.x;
    const int lane = t & 63;
    const int w = t >> 6;
    const int b = blockIdx.y;
    const int i = blockIdx.x * 4 + w;
    const int n = i + 1;
    const float* srow = S + (size_t)(b * T_ + i) * T_;

    float m = -1e30f;
    for (int j = lane; j < n; j += 64) m = fmaxf(m, srow[j]);
#pragma unroll
    for (int off = 32; off; off >>= 1) m = fmaxf(m, __shfl_xor(m, off));

    float l = 0.f;
    for (int j = lane; j < n; j += 64) {
        float p = __expf(srow[j] - m);
        pbuf[w][j] = p;
        l += p;
    }
#pragma unroll
    for (int off = 32; off; off >>= 1) l += __shfl_xor(l, off);
    const float invl = 1.0f / l;

    __syncthreads();

    const float* vb = V + b * T_ * HS_;
    float acc = 0.f;
#pragma unroll 4
    for (int j = 0; j < n; ++j) acc += pbuf[w][j] * vb[j * 64 + lane];

    out[(b * T_ + i) * 64 + lane] = acc * invl;
}

// ---------------------------------------------------------------------------
extern "C" void kernel_launch(void* const* d_in, const int* in_sizes, int n_in,
                              void* d_out, int out_size, void* d_ws, size_t ws_size,
                              hipStream_t stream)
{
    const float* x   = (const float*)d_in[0];
    const float* pos = (const float*)d_in[1];
    const float* W1  = (const float*)d_in[2];
    const float* b1  = (const float*)d_in[3];
    const float* W2  = (const float*)d_in[4];
    const float* b2  = (const float*)d_in[5];
    const float* Wv  = (const float*)d_in[6];
    float* out = (float*)d_out;
    float* ws = (float*)d_ws;

    float* Aq = ws;                 // B*T*C = 262144
    float* Ak = ws + 262144;        // 262144
    float* V  = ws + 524288;        // B*T*HS = 131072
    float* S  = ws + 655360;        // B*T*T = 1048576

    k_prep<<<dim3(128), dim3(320), 0, stream>>>(x, pos, W1, b1, Wv, Aq, Ak, V);
    k_wei<<<dim3(136, B_), dim3(256), 0, stream>>>(Aq, Ak, W2, b2, S);
    k_out<<<dim3(128, B_), dim3(256), 0, stream>>>(S, V, out);
}

// Round 2
// 50.523 us; speedup vs baseline: 1.5643x; 1.5643x over previous
//
#include <hip/hip_runtime.h>
#include <math.h>

#define B_ 4
#define T_ 512
#define C_ 128
#define HS_ 64

typedef float f4 __attribute__((ext_vector_type(4)));

// scale = C^-0.5
#define SCALE_ 0.08838834764831845f

// ---------------------------------------------------------------------------
// Kernel 1: prep.  x1 = x + pos_emb;  Aq = x1@W1q + b1;  Ak = x1@W1k; V = x@Wv
// Block: 4 rows, 320 threads, grid 512. Thread = 1 row x 4 output cols.
// q in [0,32): Aq cols q*4; [32,64): Ak cols; [64,80): V cols.
// Latency-hiding: 512 blocks (~10 waves/CU) + unroll-8 weight loads in flight.
// ---------------------------------------------------------------------------
__global__ __launch_bounds__(320) void k_prep(
    const float* __restrict__ x, const float* __restrict__ pos,
    const float* __restrict__ W1, const float* __restrict__ b1,
    const float* __restrict__ Wv,
    float* __restrict__ Aq, float* __restrict__ Ak, float* __restrict__ V)
{
    __shared__ float x1s[4 * 128];
    __shared__ float xs[4 * 128];
    const int t = threadIdx.x;
    const int row0 = blockIdx.x * 4;  // global row base over B*T = 2048

    for (int idx = t; idx < 4 * 128; idx += 320) {
        int r = idx >> 7, c = idx & 127;
        int gr = row0 + r;
        float xv = x[gr * 128 + c];
        xs[idx] = xv;
        x1s[idx] = xv + pos[(gr & 511) * 128 + c];
    }
    __syncthreads();

    const int rg = t / 80;  // row within tile (0..3)
    const int q = t % 80;

    const float* wbase;
    int wstr, col0;
    const float* xb;
    float* obase;
    int ostr;
    f4 binit = {0.f, 0.f, 0.f, 0.f};
    if (q < 32) {
        col0 = q * 4;
        wbase = W1 + 128 * 128 + col0;  // W1q rows
        wstr = 128;
        xb = x1s;
        obase = Aq;
        ostr = 128;
        binit = *(const f4*)(b1 + col0);
    } else if (q < 64) {
        col0 = (q - 32) * 4;
        wbase = W1 + col0;  // W1k rows
        wstr = 128;
        xb = x1s;
        obase = Ak;
        ostr = 128;
    } else {
        col0 = (q - 64) * 4;
        wbase = Wv + col0;
        wstr = 64;
        xb = xs;
        obase = V;
        ostr = 64;
    }

    f4 acc = binit;
    const float* xr = xb + rg * 128;
#pragma unroll 8
    for (int c = 0; c < 128; ++c) {
        f4 w = *(const f4*)(wbase + c * wstr);
        acc += xr[c] * w;
    }

    int gr = row0 + rg;
    *(f4*)(obase + gr * ostr + col0) = acc;
}

// ---------------------------------------------------------------------------
// Kernel 2: wei.  S[b,i,j] = (sum_c relu(Aq[b,i,c]+Ak[b,j,c]) * W2[c] + b2)*scale
// One block per (b, i-tile, j-tile) with j-tile <= i-tile (causal). 32x32 tile.
// 256 threads: cs = t&3 is a 32-wide c-slice; pt = t>>2 picks a 4x4 (i,j) reg
// tile. Cross-cs reduce via shfl_xor(1),(2).   (unchanged from round 1)
// ---------------------------------------------------------------------------
__global__ __launch_bounds__(256) void k_wei(
    const float* __restrict__ Aq, const float* __restrict__ Ak,
    const float* __restrict__ W2, const float* __restrict__ b2,
    float* __restrict__ S)
{
    __shared__ float aqs[32 * 132];  // padded stride 132 to break bank conflicts
    __shared__ float aks[32 * 132];
    __shared__ float w2s[128];

    const int bx = blockIdx.x;  // 0..135 lower-triangle tile index
    const int b = blockIdx.y;
    int it = (int)((sqrtf(8.0f * (float)bx + 1.0f) - 1.0f) * 0.5f);
    while ((it + 1) * (it + 2) / 2 <= bx) ++it;
    while (it * (it + 1) / 2 > bx) --it;
    const int jt = bx - it * (it + 1) / 2;
    const int i0 = it * 32, j0 = jt * 32;
    const int t = threadIdx.x;

    for (int idx = t; idx < 32 * 32; idx += 256) {
        int r = idx >> 5, cq = idx & 31;
        f4 a = *(const f4*)(Aq + ((b * T_ + i0 + r) * C_ + cq * 4));
        f4 k = *(const f4*)(Ak + ((b * T_ + j0 + r) * C_ + cq * 4));
        *(f4*)&aqs[r * 132 + cq * 4] = a;
        *(f4*)&aks[r * 132 + cq * 4] = k;
    }
    if (t < 32) *(f4*)&w2s[t * 4] = *(const f4*)(W2 + t * 4);
    __syncthreads();

    const int cs = t & 3;          // c-slice: c in [cs*32, cs*32+32)
    const int pt = t >> 2;         // 0..63
    const int i4 = (pt >> 3) * 4;  // row offset in tile
    const int j4 = (pt & 7) * 4;   // col offset in tile

    f4 w2r[8];
#pragma unroll
    for (int u = 0; u < 8; ++u) w2r[u] = *(const f4*)&w2s[cs * 32 + u * 4];

    f4 acc[4][4];
#pragma unroll
    for (int a = 0; a < 4; ++a)
#pragma unroll
        for (int k = 0; k < 4; ++k) acc[a][k] = (f4){0.f, 0.f, 0.f, 0.f};

#pragma unroll
    for (int u = 0; u < 8; ++u) {
        const int c = cs * 32 + u * 4;
        f4 Ar[4], Kr[4];
#pragma unroll
        for (int r = 0; r < 4; ++r) {
            Ar[r] = *(const f4*)&aqs[(i4 + r) * 132 + c];
            Kr[r] = *(const f4*)&aks[(j4 + r) * 132 + c];
        }
        f4 w = w2r[u];
#pragma unroll
        for (int a = 0; a < 4; ++a)
#pragma unroll
            for (int k = 0; k < 4; ++k) {
                f4 tt = Ar[a] + Kr[k];
                acc[a][k].x += fmaxf(tt.x, 0.f) * w.x;
                acc[a][k].y += fmaxf(tt.y, 0.f) * w.y;
                acc[a][k].z += fmaxf(tt.z, 0.f) * w.z;
                acc[a][k].w += fmaxf(tt.w, 0.f) * w.w;
            }
    }

    float sv[4][4];
#pragma unroll
    for (int a = 0; a < 4; ++a)
#pragma unroll
        for (int k = 0; k < 4; ++k) {
            f4 v = acc[a][k];
            float s = (v.x + v.y) + (v.z + v.w);
            s += __shfl_xor(s, 1);
            s += __shfl_xor(s, 2);
            sv[a][k] = s;
        }

    if (cs == 0) {
        const float b2v = b2[0];
#pragma unroll
        for (int a = 0; a < 4; ++a) {
            f4 o;
            o.x = (sv[a][0] + b2v) * SCALE_;
            o.y = (sv[a][1] + b2v) * SCALE_;
            o.z = (sv[a][2] + b2v) * SCALE_;
            o.w = (sv[a][3] + b2v) * SCALE_;
            *(f4*)(S + (size_t)(b * T_ + i0 + i4 + a) * T_ + j0 + j4) = o;
        }
    }
}

// ---------------------------------------------------------------------------
// Kernel 3: softmax over j (causal, row length i+1) + out = p @ v
// One BLOCK (4 waves) per row. Two-stage reductions through LDS; PV split
// across 4 waves x 4 independent accumulator chains (16 loads in flight).
// ---------------------------------------------------------------------------
__global__ __launch_bounds__(256) void k_out(
    const float* __restrict__ S, const float* __restrict__ V,
    float* __restrict__ out)
{
    __shared__ float pbuf[512];
    __shared__ float part[8];      // [0..3] wave max, [4..7] wave sum
    __shared__ float accw[4][64];

    const int t = threadIdx.x;
    const int lane = t & 63;
    const int w = t >> 6;
    const int b = blockIdx.y;
    const int i = blockIdx.x;
    const int n = i + 1;
    const float* srow = S + (size_t)(b * T_ + i) * T_;

    // pass 1: row max
    float m = -1e30f;
    for (int j = t; j < n; j += 256) m = fmaxf(m, srow[j]);
#pragma unroll
    for (int off = 32; off; off >>= 1) m = fmaxf(m, __shfl_xor(m, off));
    if (lane == 0) part[w] = m;
    __syncthreads();
    m = fmaxf(fmaxf(part[0], part[1]), fmaxf(part[2], part[3]));

    // pass 2: exp + partial sum
    float l = 0.f;
    for (int j = t; j < n; j += 256) {
        float p = __expf(srow[j] - m);
        pbuf[j] = p;
        l += p;
    }
#pragma unroll
    for (int off = 32; off; off >>= 1) l += __shfl_xor(l, off);
    if (lane == 0) part[4 + w] = l;
    __syncthreads();  // pbuf + sums ready
    const float invl = 1.0f / (part[4] + part[5] + part[6] + part[7]);

    // pass 3: PV. wave w takes j = w, w+4, w+8, ... with 4 unrolled chains.
    const float* vb = V + b * T_ * HS_;
    float s0 = 0.f, s1 = 0.f, s2 = 0.f, s3 = 0.f;
    int j = w;
    for (; j + 12 < n; j += 16) {
        s0 += pbuf[j]      * vb[(j)      * 64 + lane];
        s1 += pbuf[j + 4]  * vb[(j + 4)  * 64 + lane];
        s2 += pbuf[j + 8]  * vb[(j + 8)  * 64 + lane];
        s3 += pbuf[j + 12] * vb[(j + 12) * 64 + lane];
    }
    for (; j < n; j += 4) s0 += pbuf[j] * vb[j * 64 + lane];
    accw[w][lane] = (s0 + s1) + (s2 + s3);
    __syncthreads();

    if (w == 0) {
        float r = accw[0][lane] + accw[1][lane] + accw[2][lane] + accw[3][lane];
        out[(b * T_ + i) * 64 + lane] = r * invl;
    }
}

// ---------------------------------------------------------------------------
extern "C" void kernel_launch(void* const* d_in, const int* in_sizes, int n_in,
                              void* d_out, int out_size, void* d_ws, size_t ws_size,
                              hipStream_t stream)
{
    const float* x   = (const float*)d_in[0];
    const float* pos = (const float*)d_in[1];
    const float* W1  = (const float*)d_in[2];
    const float* b1  = (const float*)d_in[3];
    const float* W2  = (const float*)d_in[4];
    const float* b2  = (const float*)d_in[5];
    const float* Wv  = (const float*)d_in[6];
    float* out = (float*)d_out;
    float* ws = (float*)d_ws;

    float* Aq = ws;                 // B*T*C = 262144
    float* Ak = ws + 262144;        // 262144
    float* V  = ws + 524288;        // B*T*HS = 131072
    float* S  = ws + 655360;        // B*T*T = 1048576

    k_prep<<<dim3(512), dim3(320), 0, stream>>>(x, pos, W1, b1, Wv, Aq, Ak, V);
    k_wei<<<dim3(136, B_), dim3(256), 0, stream>>>(Aq, Ak, W2, b2, S);
    k_out<<<dim3(512, B_), dim3(256), 0, stream>>>(S, V, out);
}

// Round 3
// 48.217 us; speedup vs baseline: 1.6391x; 1.0478x over previous
//
#include <hip/hip_runtime.h>
#include <math.h>

#define B_ 4
#define T_ 512
#define C_ 128
#define HS_ 64

typedef float f4 __attribute__((ext_vector_type(4)));

// scale = C^-0.5
#define SCALE_ 0.08838834764831845f

// ---------------------------------------------------------------------------
// Kernel 1: prep.  x1 = x + pos_emb;  Aq = x1@W1q + b1;  Ak = x1@W1k; V = x@Wv
// 256 blocks x 640 threads (10 waves). Block = 8 rows; thread = 1 row x 4 cols.
// q = t%80 picks output colquad (0..31 Aq, 32..63 Ak, 64..79 V); r = t/80.
// W streamed from L2 once per block (~40MB total); x/x1 staged in LDS.
// unroll 8 keeps 8 weight loads in flight per thread; 10 waves/CU hide L2 lat.
// ---------------------------------------------------------------------------
__global__ __launch_bounds__(640) void k_prep(
    const float* __restrict__ x, const float* __restrict__ pos,
    const float* __restrict__ W1, const float* __restrict__ b1,
    const float* __restrict__ Wv,
    float* __restrict__ Aq, float* __restrict__ Ak, float* __restrict__ V)
{
    __shared__ float x1s[8 * 128];
    __shared__ float xs[8 * 128];
    const int t = threadIdx.x;
    const int row0 = blockIdx.x * 8;  // global row base over B*T = 2048

    if (t < 256) {  // 256 f4 = 1024 floats per buffer
        int r = t >> 5, cq = t & 31;
        int gr = row0 + r;
        f4 xv = *(const f4*)(x + gr * 128 + cq * 4);
        f4 pv = *(const f4*)(pos + (gr & 511) * 128 + cq * 4);
        *(f4*)&xs[r * 128 + cq * 4] = xv;
        *(f4*)&x1s[r * 128 + cq * 4] = xv + pv;
    }
    __syncthreads();

    const int r = t / 80;   // row within tile (0..7)
    const int q = t % 80;

    const float* wbase;
    int wstr, col0;
    const float* xb;
    float* obase;
    int ostr;
    f4 binit = {0.f, 0.f, 0.f, 0.f};
    if (q < 32) {
        col0 = q * 4;
        wbase = W1 + 128 * 128 + col0;  // W1q rows
        wstr = 128;
        xb = x1s;
        obase = Aq;
        ostr = 128;
        binit = *(const f4*)(b1 + col0);
    } else if (q < 64) {
        col0 = (q - 32) * 4;
        wbase = W1 + col0;  // W1k rows
        wstr = 128;
        xb = x1s;
        obase = Ak;
        ostr = 128;
    } else {
        col0 = (q - 64) * 4;
        wbase = Wv + col0;
        wstr = 64;
        xb = xs;
        obase = V;
        ostr = 64;
    }

    f4 acc = binit;
    const float* xr = xb + r * 128;
#pragma unroll 8
    for (int c = 0; c < 128; ++c) {
        f4 w = *(const f4*)(wbase + c * wstr);
        acc += xr[c] * w;
    }

    int gr = row0 + r;
    *(f4*)(obase + gr * ostr + col0) = acc;
}

// ---------------------------------------------------------------------------
// Kernel 2: wei.  S[b,i,j] = (sum_c relu(Aq[b,i,c]+Ak[b,j,c]) * W2[c] + b2)*scale
// One block per (b, i-tile, j-tile) with j-tile <= i-tile (causal). 32x32 tile.
// 256 threads: cs = t&3 is a 32-wide c-slice; pt = t>>2 picks a 4x4 (i,j) reg
// tile. Cross-cs reduce via shfl_xor(1),(2).   (unchanged)
// ---------------------------------------------------------------------------
__global__ __launch_bounds__(256) void k_wei(
    const float* __restrict__ Aq, const float* __restrict__ Ak,
    const float* __restrict__ W2, const float* __restrict__ b2,
    float* __restrict__ S)
{
    __shared__ float aqs[32 * 132];  // padded stride 132 to break bank conflicts
    __shared__ float aks[32 * 132];
    __shared__ float w2s[128];

    const int bx = blockIdx.x;  // 0..135 lower-triangle tile index
    const int b = blockIdx.y;
    int it = (int)((sqrtf(8.0f * (float)bx + 1.0f) - 1.0f) * 0.5f);
    while ((it + 1) * (it + 2) / 2 <= bx) ++it;
    while (it * (it + 1) / 2 > bx) --it;
    const int jt = bx - it * (it + 1) / 2;
    const int i0 = it * 32, j0 = jt * 32;
    const int t = threadIdx.x;

    for (int idx = t; idx < 32 * 32; idx += 256) {
        int r = idx >> 5, cq = idx & 31;
        f4 a = *(const f4*)(Aq + ((b * T_ + i0 + r) * C_ + cq * 4));
        f4 k = *(const f4*)(Ak + ((b * T_ + j0 + r) * C_ + cq * 4));
        *(f4*)&aqs[r * 132 + cq * 4] = a;
        *(f4*)&aks[r * 132 + cq * 4] = k;
    }
    if (t < 32) *(f4*)&w2s[t * 4] = *(const f4*)(W2 + t * 4);
    __syncthreads();

    const int cs = t & 3;          // c-slice: c in [cs*32, cs*32+32)
    const int pt = t >> 2;         // 0..63
    const int i4 = (pt >> 3) * 4;  // row offset in tile
    const int j4 = (pt & 7) * 4;   // col offset in tile

    f4 w2r[8];
#pragma unroll
    for (int u = 0; u < 8; ++u) w2r[u] = *(const f4*)&w2s[cs * 32 + u * 4];

    f4 acc[4][4];
#pragma unroll
    for (int a = 0; a < 4; ++a)
#pragma unroll
        for (int k = 0; k < 4; ++k) acc[a][k] = (f4){0.f, 0.f, 0.f, 0.f};

#pragma unroll
    for (int u = 0; u < 8; ++u) {
        const int c = cs * 32 + u * 4;
        f4 Ar[4], Kr[4];
#pragma unroll
        for (int rr = 0; rr < 4; ++rr) {
            Ar[rr] = *(const f4*)&aqs[(i4 + rr) * 132 + c];
            Kr[rr] = *(const f4*)&aks[(j4 + rr) * 132 + c];
        }
        f4 w = w2r[u];
#pragma unroll
        for (int a = 0; a < 4; ++a)
#pragma unroll
            for (int k = 0; k < 4; ++k) {
                f4 tt = Ar[a] + Kr[k];
                acc[a][k].x += fmaxf(tt.x, 0.f) * w.x;
                acc[a][k].y += fmaxf(tt.y, 0.f) * w.y;
                acc[a][k].z += fmaxf(tt.z, 0.f) * w.z;
                acc[a][k].w += fmaxf(tt.w, 0.f) * w.w;
            }
    }

    float sv[4][4];
#pragma unroll
    for (int a = 0; a < 4; ++a)
#pragma unroll
        for (int k = 0; k < 4; ++k) {
            f4 v = acc[a][k];
            float s = (v.x + v.y) + (v.z + v.w);
            s += __shfl_xor(s, 1);
            s += __shfl_xor(s, 2);
            sv[a][k] = s;
        }

    if (cs == 0) {
        const float b2v = b2[0];
#pragma unroll
        for (int a = 0; a < 4; ++a) {
            f4 o;
            o.x = (sv[a][0] + b2v) * SCALE_;
            o.y = (sv[a][1] + b2v) * SCALE_;
            o.z = (sv[a][2] + b2v) * SCALE_;
            o.w = (sv[a][3] + b2v) * SCALE_;
            *(f4*)(S + (size_t)(b * T_ + i0 + i4 + a) * T_ + j0 + j4) = o;
        }
    }
}

// ---------------------------------------------------------------------------
// Kernel 3: softmax over j (causal, row length i+1) + out = p @ v
// One BLOCK (4 waves) per row. S row register-staged (read once). PV split
// across 4 waves x 8 independent chains (32 loads in flight per block).
// ---------------------------------------------------------------------------
__global__ __launch_bounds__(256) void k_out(
    const float* __restrict__ S, const float* __restrict__ V,
    float* __restrict__ out)
{
    __shared__ float pbuf[512];
    __shared__ float part[8];      // [0..3] wave max, [4..7] wave sum
    __shared__ float accw[4][64];

    const int t = threadIdx.x;
    const int lane = t & 63;
    const int w = t >> 6;
    const int b = blockIdx.y;
    const int i = blockIdx.x;
    const int n = i + 1;
    const float* srow = S + (size_t)(b * T_ + i) * T_;

    // stage S row into regs (each thread holds up to 2 entries)
    float v0 = (t < n) ? srow[t] : -1e30f;
    float v1 = (t + 256 < n) ? srow[t + 256] : -1e30f;

    // row max
    float m = fmaxf(v0, v1);
#pragma unroll
    for (int off = 32; off; off >>= 1) m = fmaxf(m, __shfl_xor(m, off));
    if (lane == 0) part[w] = m;
    __syncthreads();
    m = fmaxf(fmaxf(part[0], part[1]), fmaxf(part[2], part[3]));

    // exp + partial sum
    float p0 = __expf(v0 - m);
    float p1 = __expf(v1 - m);
    float l = 0.f;
    if (t < n)       { pbuf[t] = p0;       l += p0; }
    if (t + 256 < n) { pbuf[t + 256] = p1; l += p1; }
#pragma unroll
    for (int off = 32; off; off >>= 1) l += __shfl_xor(l, off);
    if (lane == 0) part[4 + w] = l;
    __syncthreads();  // pbuf + sums ready
    const float invl = 1.0f / (part[4] + part[5] + part[6] + part[7]);

    // PV. wave w takes j = w mod 4, 8 unrolled chains (32 loads in flight).
    const float* vb = V + b * T_ * HS_;
    float s[8];
#pragma unroll
    for (int k = 0; k < 8; ++k) s[k] = 0.f;
    int j = w;
    for (; j + 28 < n; j += 32) {
#pragma unroll
        for (int k = 0; k < 8; ++k)
            s[k] += pbuf[j + 4 * k] * vb[(j + 4 * k) * 64 + lane];
    }
    for (; j < n; j += 4) s[0] += pbuf[j] * vb[j * 64 + lane];
    accw[w][lane] = ((s[0] + s[1]) + (s[2] + s[3])) + ((s[4] + s[5]) + (s[6] + s[7]));
    __syncthreads();

    if (w == 0) {
        float r = accw[0][lane] + accw[1][lane] + accw[2][lane] + accw[3][lane];
        out[(b * T_ + i) * 64 + lane] = r * invl;
    }
}

// ---------------------------------------------------------------------------
extern "C" void kernel_launch(void* const* d_in, const int* in_sizes, int n_in,
                              void* d_out, int out_size, void* d_ws, size_t ws_size,
                              hipStream_t stream)
{
    const float* x   = (const float*)d_in[0];
    const float* pos = (const float*)d_in[1];
    const float* W1  = (const float*)d_in[2];
    const float* b1  = (const float*)d_in[3];
    const float* W2  = (const float*)d_in[4];
    const float* b2  = (const float*)d_in[5];
    const float* Wv  = (const float*)d_in[6];
    float* out = (float*)d_out;
    float* ws = (float*)d_ws;

    float* Aq = ws;                 // B*T*C = 262144
    float* Ak = ws + 262144;        // 262144
    float* V  = ws + 524288;        // B*T*HS = 131072
    float* S  = ws + 655360;        // B*T*T = 1048576

    k_prep<<<dim3(256), dim3(640), 0, stream>>>(x, pos, W1, b1, Wv, Aq, Ak, V);
    k_wei<<<dim3(136, B_), dim3(256), 0, stream>>>(Aq, Ak, W2, b2, S);
    k_out<<<dim3(512, B_), dim3(256), 0, stream>>>(S, V, out);
}